// Round 1
// baseline (327.657 us; speedup 1.0000x reference)
//
#include <hip/hip_runtime.h>
#include <cstddef>

#define NY 64
#define NU 64
#define NHID 512
#define NH2 256
#define NT 1024
#define NBATCH 64
#define CHUNK 64
#define NCHUNK (NT / CHUNK)   // 16

// ---------------------------------------------------------------------------
// K1: per (chunk, batch) compute chunk-local scan from zero state; store the
// chunk-end state into carr[c][b][h]. Pair-per-thread (256 threads), B rows
// register-cached, no inner barriers.
// ---------------------------------------------------------------------------
__global__ __launch_bounds__(256) void k_chunk_carry(
    const float* __restrict__ U, const float* __restrict__ B,
    const float* __restrict__ lr, const float* __restrict__ li,
    float* __restrict__ carr)
{
    const int b = blockIdx.x;
    const int c = blockIdx.y;
    const int p = threadIdx.x;            // pair index 0..255
    const int t0 = c * CHUNK;

    __shared__ float u_lds[CHUNK * NU];   // 16 KB
    for (int idx = p; idx < CHUNK * NU; idx += 256) {
        const int t = idx >> 6, u = idx & 63;
        u_lds[idx] = U[(size_t)(t0 + t) * (NBATCH * NU) + b * NU + u];
    }

    // register-cache B rows p and p+256
    float B1[NU], B2[NU];
    #pragma unroll
    for (int u = 0; u < NU; u += 4) {
        const float4 v1 = *reinterpret_cast<const float4*>(&B[p * NU + u]);
        B1[u] = v1.x; B1[u + 1] = v1.y; B1[u + 2] = v1.z; B1[u + 3] = v1.w;
        const float4 v2 = *reinterpret_cast<const float4*>(&B[(p + NH2) * NU + u]);
        B2[u] = v2.x; B2[u + 1] = v2.y; B2[u + 2] = v2.z; B2[u + 3] = v2.w;
    }
    const float Lr = lr[p], Li = li[p];

    __syncthreads();

    float x1 = 0.f, x2 = 0.f;
    for (int t = 0; t < CHUNK; ++t) {
        const float* uv = &u_lds[t * NU];
        float bu1 = 0.f, bu2 = 0.f;
        #pragma unroll
        for (int u = 0; u < NU; ++u) {
            const float uu = uv[u];
            bu1 += B1[u] * uu;
            bu2 += B2[u] * uu;
        }
        const float nx1 = Lr * x1 - Li * x2 + bu1;
        const float nx2 = Li * x1 + Lr * x2 + bu2;
        x1 = nx1; x2 = nx2;
    }
    const size_t base = (size_t)c * (NBATCH * NHID) + (size_t)b * NHID;
    carr[base + p] = x1;
    carr[base + NH2 + p] = x2;
}

// ---------------------------------------------------------------------------
// K2: sequential carry propagation over the 16 chunks, in place.
// After this, carr[c][b][h] holds the exact state ENTERING chunk c.
// Also computes x0 = y0 @ Wy2x^T + by2x and Lambda^CHUNK by squaring.
// ---------------------------------------------------------------------------
__global__ __launch_bounds__(256) void k_carry_prop(
    const float* __restrict__ y0, const float* __restrict__ Wy2x,
    const float* __restrict__ by2x,
    const float* __restrict__ lr, const float* __restrict__ li,
    float* __restrict__ carr)
{
    const int b = blockIdx.x;
    const int p = threadIdx.x;            // 0..255
    const int h1 = p, h2 = p + NH2;

    // x0 for this (b, pair)
    float x1 = by2x[h1], x2 = by2x[h2];
    #pragma unroll 8
    for (int y = 0; y < NY; ++y) {
        const float yv = y0[b * NY + y];
        x1 += yv * Wy2x[h1 * NY + y];
        x2 += yv * Wy2x[h2 * NY + y];
    }

    // Lambda^CHUNK (CHUNK = 64 = 2^6) by repeated squaring
    float cr = lr[p], ci = li[p];
    #pragma unroll
    for (int k = 0; k < 6; ++k) {
        const float nr = cr * cr - ci * ci;
        const float ni = 2.f * cr * ci;
        cr = nr; ci = ni;
    }

    for (int c = 0; c < NCHUNK; ++c) {
        const size_t base = (size_t)c * (NBATCH * NHID) + (size_t)b * NHID;
        const float le1 = carr[base + h1];
        const float le2 = carr[base + h2];
        carr[base + h1] = x1;             // overwrite with carry-in for chunk c
        carr[base + h2] = x2;
        const float nx1 = cr * x1 - ci * x2 + le1;
        const float nx2 = ci * x1 + cr * x2 + le2;
        x1 = nx1; x2 = nx2;
    }
}

// ---------------------------------------------------------------------------
// K3: per (chunk, batch): rerun the exact recurrence seeded with the exact
// carry-in, and fuse Y[t] = x_t @ Wx2y^T + bx2y.
// 512 threads, h-mapped for the scan; (g = tid>>6, j = tid&63) mapped for the
// output GEMM partial reduction.
// ---------------------------------------------------------------------------
__global__ __launch_bounds__(512) void k_final(
    const float* __restrict__ U, const float* __restrict__ B,
    const float* __restrict__ lr, const float* __restrict__ li,
    const float* __restrict__ Wx2y, const float* __restrict__ bx2y,
    const float* __restrict__ carr, float* __restrict__ Y)
{
    const int b = blockIdx.x;
    const int c = blockIdx.y;
    const int tid = threadIdx.x;          // 0..511
    const int h = tid;
    const int t0 = c * CHUNK;

    __shared__ float u_lds[CHUNK * NU];   // 16 KB
    __shared__ float x_lds[NHID];         // 2 KB
    __shared__ float part[NY * 8];        // 2 KB

    for (int idx = tid; idx < CHUNK * NU; idx += 512) {
        const int t = idx >> 6, u = idx & 63;
        u_lds[idx] = U[(size_t)(t0 + t) * (NBATCH * NU) + b * NU + u];
    }

    // register-cache B row h
    float Brow[NU];
    #pragma unroll
    for (int u = 0; u < NU; u += 4) {
        const float4 v = *reinterpret_cast<const float4*>(&B[h * NU + u]);
        Brow[u] = v.x; Brow[u + 1] = v.y; Brow[u + 2] = v.z; Brow[u + 3] = v.w;
    }
    // register-cache Wx2y[j, g*64 .. g*64+63]
    const int j = tid & 63, g = tid >> 6;
    float Wsl[64];
    #pragma unroll
    for (int u = 0; u < 64; u += 4) {
        const float4 v = *reinterpret_cast<const float4*>(&Wx2y[j * NHID + g * 64 + u]);
        Wsl[u] = v.x; Wsl[u + 1] = v.y; Wsl[u + 2] = v.z; Wsl[u + 3] = v.w;
    }
    const float bias = bx2y[j];

    const int p = h & (NH2 - 1);
    const bool lo = (h < NH2);
    const int partner = lo ? (h + NH2) : (h - NH2);
    const float Lr = lr[p], Li = li[p];

    float x_self = carr[(size_t)c * (NBATCH * NHID) + (size_t)b * NHID + h];
    x_lds[h] = x_self;
    __syncthreads();

    for (int t = 0; t < CHUNK; ++t) {
        // bu for this h
        const float* uv = &u_lds[t * NU];
        float bu = 0.f;
        #pragma unroll
        for (int u = 0; u < NU; ++u) bu += Brow[u] * uv[u];

        const float xp = x_lds[partner];
        const float nx = lo ? (Lr * x_self - Li * xp + bu)
                            : (Li * xp + Lr * x_self + bu);
        __syncthreads();                  // (A) all reads of old x done
        x_self = nx;
        x_lds[h] = nx;
        __syncthreads();                  // (B) new x visible

        // output GEMM partial: thread (j,g) reduces h in [g*64, g*64+64)
        float s = 0.f;
        #pragma unroll
        for (int u = 0; u < 64; ++u) s += Wsl[u] * x_lds[(g << 6) + u];
        part[(j << 3) + g] = s;
        __syncthreads();                  // (C) partials visible

        if (tid < NY) {
            float yv = bias;
            #pragma unroll
            for (int g2 = 0; g2 < 8; ++g2) yv += part[(tid << 3) + g2];
            Y[(size_t)(t0 + t) * (NBATCH * NY) + (size_t)b * NY + tid] = yv;
        }
        // part/x_lds rewritten only after >=2 barriers next iteration: safe.
    }
}

extern "C" void kernel_launch(void* const* d_in, const int* in_sizes, int n_in,
                              void* d_out, int out_size, void* d_ws, size_t ws_size,
                              hipStream_t stream) {
    const float* y0   = (const float*)d_in[0];
    const float* U    = (const float*)d_in[1];
    const float* lr   = (const float*)d_in[2];
    const float* li   = (const float*)d_in[3];
    const float* B    = (const float*)d_in[4];
    const float* Wy2x = (const float*)d_in[5];
    const float* by2x = (const float*)d_in[6];
    const float* Wx2y = (const float*)d_in[7];
    const float* bx2y = (const float*)d_in[8];
    float* Y = (float*)d_out;
    float* carr = (float*)d_ws;           // NCHUNK*NBATCH*NHID floats = 2 MB

    dim3 grid(NBATCH, NCHUNK);
    k_chunk_carry<<<grid, 256, 0, stream>>>(U, B, lr, li, carr);
    k_carry_prop<<<NBATCH, 256, 0, stream>>>(y0, Wy2x, by2x, lr, li, carr);
    k_final<<<grid, 512, 0, stream>>>(U, B, lr, li, Wx2y, bx2y, carr, Y);
}

// Round 2
// 67.530 us; speedup vs baseline: 4.8520x; 4.8520x over previous
//
#include <hip/hip_runtime.h>
#include <hip/hip_bf16.h>
#include <cstddef>
#include <cstdint>

#define NYV 64
#define NUV 64
#define NHID 512
#define NH2 256
#define NTT 1024
#define NBATCH 64
#define CHUNK 64
#define NCHUNK 16
#define XP 520              // Xl row pitch (bf16 units) -> 1040 B, breaks pow2 stride
#define UP 72               // Ul row pitch (bf16 units) -> 144 B

typedef __attribute__((ext_vector_type(8))) short bf16x8;
typedef __attribute__((ext_vector_type(4))) float f32x4;
typedef __attribute__((ext_vector_type(8))) short short8v;

__device__ __forceinline__ uint f2bf(float f) {
    union { __hip_bfloat16 h; ushort s; } u;
    u.h = __float2bfloat16(f);
    return (uint)u.s;
}
__device__ __forceinline__ float bf2f_lo(uint d) {
    union { uint u; float f; } v; v.u = d << 16; return v.f;
}
__device__ __forceinline__ float bf2f_hi(uint d) {
    union { uint u; float f; } v; v.u = d & 0xffff0000u; return v.f;
}

// h-permutation: h' = 2p   <-> orig h = p      (real of pair p)
//                h' = 2p+1 <-> orig h = p+256  (imag of pair p)
// orig(h') = (h'>>1) + (h'&1)*256

// ---------------------------------------------------------------------------
// Fused per-(chunk,batch) kernel.
//   GEMM1 (MFMA): Bu^T[h'][t] = sum_u Bperm[h'][u] * U[t][u]  -> Xl bf16
//   scan  (VALU): pair-per-thread over t, f32 carry registers
//   FINAL=false: write chunk-end state to carr, done.
//   FINAL=true : seed from carr, write x_t back to Xl (bf16),
//                GEMM2 (MFMA): Y[t][y] = sum_h' X[t][h'] * Wperm[y][h'] + b
// ---------------------------------------------------------------------------
template<bool FINAL>
__global__ __launch_bounds__(256) void k_scan(
    const float* __restrict__ U, const float* __restrict__ B,
    const float* __restrict__ lr, const float* __restrict__ li,
    const float* __restrict__ W, const float* __restrict__ bx2y,
    float* __restrict__ carr, float* __restrict__ Y)
{
    __shared__ short Xl[CHUNK * XP];   // 66,560 B
    __shared__ short Ul[CHUNK * UP];   //  9,216 B

    const int b  = blockIdx.x;
    const int c  = blockIdx.y;
    const int t0 = c * CHUNK;
    const int tid  = threadIdx.x;
    const int lane = tid & 63;
    const int w    = tid >> 6;          // wave 0..3
    const int lm   = lane & 15;
    const int lg   = lane >> 4;

    // ---- stage U chunk (f32 -> bf16) into Ul[t][u] ----
    {
        const int t = tid >> 2, q = (tid & 3) * 16;
        const float* up = U + ((size_t)(t0 + t) * NBATCH + b) * NUV + q;
        const float4 f0 = *(const float4*)(up + 0);
        const float4 f1 = *(const float4*)(up + 4);
        const float4 f2 = *(const float4*)(up + 8);
        const float4 f3 = *(const float4*)(up + 12);
        short8v s0, s1;
        s0[0]=(short)f2bf(f0.x); s0[1]=(short)f2bf(f0.y);
        s0[2]=(short)f2bf(f0.z); s0[3]=(short)f2bf(f0.w);
        s0[4]=(short)f2bf(f1.x); s0[5]=(short)f2bf(f1.y);
        s0[6]=(short)f2bf(f1.z); s0[7]=(short)f2bf(f1.w);
        s1[0]=(short)f2bf(f2.x); s1[1]=(short)f2bf(f2.y);
        s1[2]=(short)f2bf(f2.z); s1[3]=(short)f2bf(f2.w);
        s1[4]=(short)f2bf(f3.x); s1[5]=(short)f2bf(f3.y);
        s1[6]=(short)f2bf(f3.z); s1[7]=(short)f2bf(f3.w);
        *(short8v*)&Ul[t*UP + q]     = s0;
        *(short8v*)&Ul[t*UP + q + 8] = s1;
    }
    __syncthreads();

    // ---- GEMM1: wave w owns h'-tiles [w*8, w*8+8), all 4 t-tiles ----
    // A-frag (M=h',K=u): lane -> row h'=mt*16+lm, k = lg*8+j (+32*ks), from B global
    // B-frag (K=u,N=t) : lane -> col t=nt*16+lm, k = lg*8+j (+32*ks), from Ul
    {
        bf16x8 ufrag[4][2];
        #pragma unroll
        for (int nt = 0; nt < 4; ++nt)
            #pragma unroll
            for (int ks = 0; ks < 2; ++ks)
                ufrag[nt][ks] = *(const bf16x8*)&Ul[(nt*16 + lm)*UP + lg*8 + ks*32];

        #pragma unroll
        for (int i = 0; i < 8; ++i) {
            const int mt = w*8 + i;
            const int hp = mt*16 + lm;                    // A-row h'
            const int ho = (hp >> 1) + ((hp & 1) << 8);   // orig h
            bf16x8 a[2];
            #pragma unroll
            for (int ks = 0; ks < 2; ++ks) {
                const float* bp = B + ho*NUV + lg*8 + ks*32;
                const float4 g0 = *(const float4*)(bp);
                const float4 g1 = *(const float4*)(bp + 4);
                bf16x8 t8;
                t8[0]=(short)f2bf(g0.x); t8[1]=(short)f2bf(g0.y);
                t8[2]=(short)f2bf(g0.z); t8[3]=(short)f2bf(g0.w);
                t8[4]=(short)f2bf(g1.x); t8[5]=(short)f2bf(g1.y);
                t8[6]=(short)f2bf(g1.z); t8[7]=(short)f2bf(g1.w);
                a[ks] = t8;
            }
            #pragma unroll
            for (int nt = 0; nt < 4; ++nt) {
                f32x4 acc = {0.f, 0.f, 0.f, 0.f};
                acc = __builtin_amdgcn_mfma_f32_16x16x32_bf16(a[0], ufrag[nt][0], acc, 0, 0, 0);
                acc = __builtin_amdgcn_mfma_f32_16x16x32_bf16(a[1], ufrag[nt][1], acc, 0, 0, 0);
                // D[m=h'][n=t]: lane -> h' = mt*16 + lg*4 + r, t = nt*16 + lm
                const int t  = nt*16 + lm;
                const int hb = mt*16 + lg*4;
                uint2 pk;
                pk.x = f2bf(acc[0]) | (f2bf(acc[1]) << 16);
                pk.y = f2bf(acc[2]) | (f2bf(acc[3]) << 16);
                *(uint2*)&Xl[t*XP + hb] = pk;             // ds_write_b64, 8B aligned
            }
        }
    }
    __syncthreads();

    // ---- scan: thread p owns complex pair (h'=2p, 2p+1) ----
    {
        const int p = tid;
        const float Lr = lr[p], Li = li[p];
        float x1, x2;
        if (FINAL) {
            const float* cp = carr + ((size_t)c*NBATCH + b)*NHID + 2*p;
            x1 = cp[0]; x2 = cp[1];
        } else { x1 = 0.f; x2 = 0.f; }
        #pragma unroll 8
        for (int t = 0; t < CHUNK; ++t) {
            const uint d = *(const uint*)&Xl[t*XP + 2*p];
            const float n1 = fmaf(Lr, x1, fmaf(-Li, x2, bf2f_lo(d)));
            const float n2 = fmaf(Li, x1, fmaf( Lr, x2, bf2f_hi(d)));
            x1 = n1; x2 = n2;
            if (FINAL) {
                const uint pk = f2bf(x1) | (f2bf(x2) << 16);
                *(uint*)&Xl[t*XP + 2*p] = pk;
            }
        }
        if (!FINAL) {
            float* cp = carr + ((size_t)c*NBATCH + b)*NHID + 2*p;
            cp[0] = x1; cp[1] = x2;
        }
    }

    if constexpr (FINAL) {
        __syncthreads();
        // ---- GEMM2: wave w owns y-tile w; M-tiles (t) 0..3; K = 512 ----
        const int y = w*16 + lm;
        const float bias = bx2y[y];
        f32x4 acc[4];
        #pragma unroll
        for (int mt = 0; mt < 4; ++mt) acc[mt] = (f32x4){bias, bias, bias, bias};

        #pragma unroll
        for (int ks = 0; ks < 16; ++ks) {
            // B-frag: k = h' = lg*8 + 32*ks + j ; j even->real W[y][p0+..], odd->imag
            const int p0 = lg*4 + ks*16;
            const float4 wr = *(const float4*)(W + (size_t)y*NHID + p0);
            const float4 wi = *(const float4*)(W + (size_t)y*NHID + NH2 + p0);
            bf16x8 bf;
            bf[0]=(short)f2bf(wr.x); bf[1]=(short)f2bf(wi.x);
            bf[2]=(short)f2bf(wr.y); bf[3]=(short)f2bf(wi.y);
            bf[4]=(short)f2bf(wr.z); bf[5]=(short)f2bf(wi.z);
            bf[6]=(short)f2bf(wr.w); bf[7]=(short)f2bf(wi.w);
            const int kb = lg*8 + ks*32;
            #pragma unroll
            for (int mt = 0; mt < 4; ++mt) {
                const bf16x8 xa = *(const bf16x8*)&Xl[(mt*16 + lm)*XP + kb];
                acc[mt] = __builtin_amdgcn_mfma_f32_16x16x32_bf16(xa, bf, acc[mt], 0, 0, 0);
            }
        }
        #pragma unroll
        for (int mt = 0; mt < 4; ++mt) {
            #pragma unroll
            for (int r = 0; r < 4; ++r) {
                const int t = mt*16 + lg*4 + r;
                Y[((size_t)(t0 + t)*NBATCH + b)*NYV + y] = acc[mt][r];
            }
        }
    }
}

// ---------------------------------------------------------------------------
// Carry propagation: x0 = y0@Wy2x^T + by2x; sequential over 16 chunks.
// carr[c][b][2p+{0,1}] : in = chunk-local end states, out = chunk ENTRY states.
// ---------------------------------------------------------------------------
__global__ __launch_bounds__(256) void k_carry_prop(
    const float* __restrict__ y0, const float* __restrict__ Wy2x,
    const float* __restrict__ by2x,
    const float* __restrict__ lr, const float* __restrict__ li,
    float* __restrict__ carr)
{
    const int b = blockIdx.x;
    const int p = threadIdx.x;            // 0..255

    float x1 = by2x[p], x2 = by2x[p + NH2];
    #pragma unroll 8
    for (int y = 0; y < NYV; ++y) {
        const float yv = y0[b * NYV + y];
        x1 = fmaf(yv, Wy2x[p * NYV + y], x1);
        x2 = fmaf(yv, Wy2x[(p + NH2) * NYV + y], x2);
    }

    // Lambda^64 by 6 squarings
    float cr = lr[p], ci = li[p];
    #pragma unroll
    for (int k = 0; k < 6; ++k) {
        const float nr = cr*cr - ci*ci;
        const float ni = 2.f*cr*ci;
        cr = nr; ci = ni;
    }

    for (int c = 0; c < NCHUNK; ++c) {
        float* cp = carr + ((size_t)c*NBATCH + b)*NHID + 2*p;
        const float le1 = cp[0];
        const float le2 = cp[1];
        cp[0] = x1; cp[1] = x2;
        const float n1 = cr*x1 - ci*x2 + le1;
        const float n2 = ci*x1 + cr*x2 + le2;
        x1 = n1; x2 = n2;
    }
}

extern "C" void kernel_launch(void* const* d_in, const int* in_sizes, int n_in,
                              void* d_out, int out_size, void* d_ws, size_t ws_size,
                              hipStream_t stream) {
    const float* y0   = (const float*)d_in[0];
    const float* U    = (const float*)d_in[1];
    const float* lr   = (const float*)d_in[2];
    const float* li   = (const float*)d_in[3];
    const float* B    = (const float*)d_in[4];
    const float* Wy2x = (const float*)d_in[5];
    const float* by2x = (const float*)d_in[6];
    const float* Wx2y = (const float*)d_in[7];
    const float* bx2y = (const float*)d_in[8];
    float* Y    = (float*)d_out;
    float* carr = (float*)d_ws;           // 16*64*512 f32 = 2 MB (proven ws size)

    dim3 grid(NBATCH, NCHUNK);
    k_scan<false><<<grid, 256, 0, stream>>>(U, B, lr, li, Wx2y, bx2y, carr, Y);
    k_carry_prop<<<NBATCH, 256, 0, stream>>>(y0, Wy2x, by2x, lr, li, carr);
    k_scan<true ><<<grid, 256, 0, stream>>>(U, B, lr, li, Wx2y, bx2y, carr, Y);
}